// Round 2
// baseline (9997.536 us; speedup 1.0000x reference)
//
#include <hip/hip_runtime.h>

// Stacked 2-layer tanh RNN, SEQ=512, B=64, IN=H=1024.
// Round 2: batch-split across XCDs (8 rows per XCD), h-state coherent via the
// XCD's own L2 (sc0 stores/loads), step counters via LLC (sc1 atomics/polls).
// Per XCD: 16 L0-CUs + 16 L1-CUs (64 features each), pipelined 1 step apart.
// Weights held in VGPRs as bf16 MFMA B-frags (32 frags = 128 VGPR/lane).

typedef unsigned short ushort_t;
typedef unsigned int uint32;
typedef __attribute__((ext_vector_type(4))) unsigned int u32x4;
typedef __attribute__((ext_vector_type(4))) float f32x4;
typedef __attribute__((ext_vector_type(8))) __bf16 bfrag;

__device__ __forceinline__ f32x4 mfma_bf16(u32x4 a, u32x4 b, f32x4 c) {
  return __builtin_amdgcn_mfma_f32_16x16x32_bf16(
      __builtin_bit_cast(bfrag, a), __builtin_bit_cast(bfrag, b), c, 0, 0, 0);
}

__device__ __forceinline__ uint32 bf16rne(float f) {
  uint32 u = __builtin_bit_cast(uint32, f);
  return (u + 0x7fffu + ((u >> 16) & 1u)) >> 16;
}

__device__ __forceinline__ uint32 cvt_pk(float lo, float hi) {
  uint32 r;
  asm("v_cvt_pk_bf16_f32 %0, %1, %2" : "=v"(r) : "v"(lo), "v"(hi));
  return r;
}
__device__ __forceinline__ u32x4 pack8(f32x4 a, f32x4 b) {
  u32x4 r;
  r.x = cvt_pk(a.x, a.y);
  r.y = cvt_pk(a.z, a.w);
  r.z = cvt_pk(b.x, b.y);
  r.w = cvt_pk(b.z, b.w);
  return r;
}

// 16B L2-coherent load (bypass L1) with compile-time byte offset.
template <int BOFF>
__device__ __forceinline__ void ld16(u32x4& d, const ushort_t* base) {
  asm volatile("global_load_dwordx4 %0, %1, off offset:%c2 sc0"
               : "=v"(d) : "v"(base), "i"(BOFF) : "memory");
}

#define LOADB(BUF, AP, KOFF)                 \
  ld16<(KOFF) * 2 + 0>(BUF[0], AP);          \
  ld16<(KOFF) * 2 + 64>(BUF[1], AP);         \
  ld16<(KOFF) * 2 + 128>(BUF[2], AP);        \
  ld16<(KOFF) * 2 + 192>(BUF[3], AP);        \
  ld16<(KOFF) * 2 + 256>(BUF[4], AP);        \
  ld16<(KOFF) * 2 + 320>(BUF[5], AP);        \
  ld16<(KOFF) * 2 + 384>(BUF[6], AP);        \
  ld16<(KOFF) * 2 + 448>(BUF[7], AP);

// Bounded LLC poll (1 line per wave, all lanes same address).
__device__ __forceinline__ void spin_ctr(const int* p, int tgt, int* ab) {
  int it = 0;
  for (;;) {
    int v;
    asm volatile("global_load_dword %0, %1, off sc0 sc1\n\ts_waitcnt vmcnt(0)"
                 : "=v"(v) : "v"(p) : "memory");
    if (v >= tgt) return;
    if ((++it & 1023) == 0) {
      int a;
      asm volatile("global_load_dword %0, %1, off sc0 sc1\n\ts_waitcnt vmcnt(0)"
                   : "=v"(a) : "v"(ab) : "memory");
      if (a) return;
      if (it > (1 << 21)) {
        int one = 1;
        asm volatile("global_store_dword %0, %1, off sc0 sc1\n\ts_waitcnt vmcnt(0)"
                     :: "v"(ab), "v"(one) : "memory");
        return;
      }
    }
  }
}

__global__ void rnn_init(int* c) {
  // zero slot/ctr0/ctr1 (8 XCDs x 3 x 32 ints) + abort flag, at LLC scope
  for (int k = threadIdx.x; k < 772; k += 256) {
    int z = 0;
    asm volatile("global_store_dword %0, %1, off sc0 sc1"
                 :: "v"(c + k), "v"(z) : "memory");
  }
  asm volatile("s_waitcnt vmcnt(0)" ::: "memory");
}

__global__ __launch_bounds__(512, 2) void rnn_main(
    const float* __restrict__ Xt, const float* __restrict__ W0,
    const float* __restrict__ b0, const float* __restrict__ W1,
    const float* __restrict__ b1, float* __restrict__ Y,
    ushort_t* hbuf, int* cnt) {
  __shared__ float part[2][4][16][17];  // [buf][ntile][row16][feat16+pad]
  __shared__ int s_slot;

  const int tid = threadIdx.x;
  const int wave = tid >> 6;
  const int lane = tid & 63;
  const int ln15 = lane & 15;
  const int lq = lane >> 4;
  const int n = wave & 3;
  const bool fin = wave < 4;  // finisher waves (h-half K, tanh, stores)

  uint32 xcc;
  asm("s_getreg_b32 %0, hwreg(HW_REG_XCC_ID)" : "=s"(xcc));
  const int xcd = xcc & 7;

  int* slotp  = cnt + xcd * 96;
  int* ctr0   = cnt + xcd * 96 + 32;
  int* ctr1   = cnt + xcd * 96 + 64;
  int* abortp = cnt + 768;

  if (tid == 0) {
    int one = 1, old;
    asm volatile("global_atomic_add %0, %1, %2, off sc0 sc1\n\ts_waitcnt vmcnt(0)"
                 : "=v"(old) : "v"(slotp), "v"(one) : "memory");
    s_slot = old & 31;
  }
  __syncthreads();
  const int slot = s_slot;
  const bool isL1 = slot >= 16;
  const int F0 = (slot & 15) * 64;
  const int fcol = F0 + n * 16 + ln15;
  const int row8 = ln15 & 7;  // batch row (rows 8-15 of MFMA tile are dup/discard)

  // K-half owned by this wave:
  //  L0: fin -> h0(t-1) half (k 1024..2047), partial -> x half (k 0..1023)
  //  L1: fin -> h0(t) half (k 0..1023),     partial -> h1(t-1) half (k 1024..2047)
  const int kh = isL1 ? (fin ? 0 : 1) : (fin ? 1 : 0);
  const float* Wsrc = isL1 ? W1 : W0;

  // Load + pack this wave's weight slice into 32 B-frags (128 VGPRs).
  u32x4 bw[32];
  {
    const float* wp = Wsrc + (size_t)fcol * 2048 + kh * 1024 + lq * 8;
#pragma unroll 4
    for (int j = 0; j < 32; ++j) {
      f32x4 w0 = *(const f32x4*)(wp + j * 32);
      f32x4 w1 = *(const f32x4*)(wp + j * 32 + 4);
      bw[j] = pack8(w0, w1);
    }
  }
  const float bia = fin ? (isL1 ? b1 : b0)[fcol] : 0.f;

  ushort_t* h0b = hbuf + (size_t)xcd * 32768;  // [2][8][1024] bf16
  ushort_t* h1b = h0b + 16384;                 // [2][8][1024] bf16

  // K=1024 GEMM against L2-coherent h-state, 2-bank pipelined sc0 loads.
  auto gemm_h = [&](const ushort_t* hsrc) -> f32x4 {
    f32x4 a = {0.f, 0.f, 0.f, 0.f};
    const ushort_t* ap = hsrc + row8 * 1024 + lq * 8;
    u32x4 fa[8], fb[8];
    LOADB(fa, ap, 0);
    LOADB(fb, ap, 256);
    asm volatile("s_waitcnt vmcnt(8)" ::: "memory");
    __builtin_amdgcn_sched_barrier(0);
#pragma unroll
    for (int j = 0; j < 8; ++j) a = mfma_bf16(fa[j], bw[j], a);
    LOADB(fa, ap, 512);
    asm volatile("s_waitcnt vmcnt(8)" ::: "memory");
    __builtin_amdgcn_sched_barrier(0);
#pragma unroll
    for (int j = 0; j < 8; ++j) a = mfma_bf16(fb[j], bw[8 + j], a);
    LOADB(fb, ap, 768);
    asm volatile("s_waitcnt vmcnt(8)" ::: "memory");
    __builtin_amdgcn_sched_barrier(0);
#pragma unroll
    for (int j = 0; j < 8; ++j) a = mfma_bf16(fa[j], bw[16 + j], a);
    asm volatile("s_waitcnt vmcnt(0)" ::: "memory");
    __builtin_amdgcn_sched_barrier(0);
#pragma unroll
    for (int j = 0; j < 8; ++j) a = mfma_bf16(fb[j], bw[24 + j], a);
    return a;
  };

  // K=1024 GEMM against f32 X with on-the-fly bf16 pack (off critical path).
  auto gemm_x = [&](int t) -> f32x4 {
    f32x4 a = {0.f, 0.f, 0.f, 0.f};
    const float* xp = Xt + ((size_t)t * 64 + xcd * 8 + row8) * 1024 + lq * 8;
#pragma unroll 4
    for (int j = 0; j < 32; ++j) {
      f32x4 x0 = *(const f32x4*)(xp + j * 32);
      f32x4 x1 = *(const f32x4*)(xp + j * 32 + 4);
      a = mfma_bf16(pack8(x0, x1), bw[j], a);
    }
    return a;
  };

  for (int t = 0; t < 512; ++t) {
    const int buf = t & 1;
    const int pb = (t - 1) & 1;
    f32x4 acc = {0.f, 0.f, 0.f, 0.f};

    if (!isL1) {
      if (fin) {
        if (t >= 1) spin_ctr(ctr0, 16 * t, abortp);        // h0(t-1) ready
        if (t >= 2) spin_ctr(ctr1, 16 * (t - 1), abortp);  // h0 slot reusable
        if (t >= 1) acc = gemm_h(h0b + pb * 8192);
      } else {
        acc = gemm_x(t);
      }
    } else {
      if (fin) {
        if (t >= 1) spin_ctr(ctr1, 16 * t, abortp);        // own cohort done t-1
        spin_ctr(ctr0, 16 * (t + 1), abortp);              // h0(t) ready
        acc = gemm_h(h0b + buf * 8192);
      } else {
        if (t >= 1) {
          spin_ctr(ctr1, 16 * t, abortp);                  // h1(t-1) ready
          acc = gemm_h(h1b + pb * 8192);
        }
      }
    }

    if (!fin) {
#pragma unroll
      for (int r = 0; r < 4; ++r) part[buf][n][lq * 4 + r][ln15] = acc[r];
    }
    __syncthreads();  // partial tiles visible

    if (fin) {
      float o[4];
#pragma unroll
      for (int r = 0; r < 4; ++r) {
        float s = acc[r] + part[buf][n][lq * 4 + r][ln15] + bia;
        float ax = fabsf(s);
        float e = __expf(2.f * ax);                  // inf-safe
        float rr = 1.f - 2.f * __builtin_amdgcn_rcpf(e + 1.f);
        o[r] = copysignf(rr, s);
      }
      if (lq < 2) {  // valid batch rows 0..7
        ushort_t* hd = (isL1 ? h1b : h0b) + buf * 8192 + (lq * 4) * 1024 + fcol;
#pragma unroll
        for (int r = 0; r < 4; ++r) {
          uint32 hv = bf16rne(o[r]);
          asm volatile("global_store_short %0, %1, off sc0"
                       :: "v"(hd + r * 1024), "v"(hv) : "memory");
        }
        if (isL1) {
          float* yd = Y + ((size_t)t * 64 + xcd * 8 + lq * 4) * 1024 + fcol;
#pragma unroll
          for (int r = 0; r < 4; ++r) yd[r * 1024] = o[r];
        }
      }
      asm volatile("s_waitcnt vmcnt(0)" ::: "memory");  // h in L2, Y accepted
    }
    __syncthreads();  // all fin stores drained

    if (tid == 0) {
      int one = 1;
      int* cp = isL1 ? ctr1 : ctr0;
      asm volatile("global_atomic_add %0, %1, off sc1" :: "v"(cp), "v"(one) : "memory");
    }
  }
}

extern "C" void kernel_launch(void* const* d_in, const int* in_sizes, int n_in,
                              void* d_out, int out_size, void* d_ws, size_t ws_size,
                              hipStream_t stream) {
  const float* Xt = (const float*)d_in[0];
  const float* W0 = (const float*)d_in[1];
  const float* b0 = (const float*)d_in[2];
  const float* W1 = (const float*)d_in[3];
  const float* b1 = (const float*)d_in[4];
  float* Y = (float*)d_out;

  int* cnt = (int*)d_ws;                                   // 3088 B used
  ushort_t* hbuf = (ushort_t*)((char*)d_ws + 4096);        // 512 KB h-state

  rnn_init<<<1, 256, 0, stream>>>(cnt);
  rnn_main<<<256, 512, 0, stream>>>(Xt, W0, b0, W1, b1, Y, hbuf, cnt);
}

// Round 3
// 9986.582 us; speedup vs baseline: 1.0011x; 1.0011x over previous
//
#include <hip/hip_runtime.h>

// Stacked 2-layer tanh RNN, SEQ=512, B=64, IN=H=1024.
// Round 3: round-2 structure (batch-split across 8 XCDs, h-state in the XCD's
// own L2 via sc0, per-XCD 16-block cohorts for L0/L1 pipelined one step apart,
// weights in VGPRs) with the spill fixed: __launch_bounds__(512) -> 256-VGPR
// cap, so the 32 weight B-frags (128 VGPRs) stay in registers.

typedef unsigned short ushort_t;
typedef unsigned int uint32;
typedef __attribute__((ext_vector_type(4))) unsigned int u32x4;
typedef __attribute__((ext_vector_type(4))) float f32x4;
typedef __attribute__((ext_vector_type(8))) __bf16 bfrag;

__device__ __forceinline__ f32x4 mfma_bf16(u32x4 a, u32x4 b, f32x4 c) {
  return __builtin_amdgcn_mfma_f32_16x16x32_bf16(
      __builtin_bit_cast(bfrag, a), __builtin_bit_cast(bfrag, b), c, 0, 0, 0);
}

__device__ __forceinline__ uint32 bf16rne(float f) {
  uint32 u = __builtin_bit_cast(uint32, f);
  return (u + 0x7fffu + ((u >> 16) & 1u)) >> 16;
}

__device__ __forceinline__ uint32 cvt_pk(float lo, float hi) {
  uint32 r;
  asm("v_cvt_pk_bf16_f32 %0, %1, %2" : "=v"(r) : "v"(lo), "v"(hi));
  return r;
}
__device__ __forceinline__ u32x4 pack8(f32x4 a, f32x4 b) {
  u32x4 r;
  r.x = cvt_pk(a.x, a.y);
  r.y = cvt_pk(a.z, a.w);
  r.z = cvt_pk(b.x, b.y);
  r.w = cvt_pk(b.z, b.w);
  return r;
}

// 16B L2-coherent load (bypass L1) with compile-time byte offset.
template <int BOFF>
__device__ __forceinline__ void ld16(u32x4& d, const ushort_t* base) {
  asm volatile("global_load_dwordx4 %0, %1, off offset:%c2 sc0"
               : "=v"(d) : "v"(base), "i"(BOFF) : "memory");
}

#define LOADB(BUF, AP, KOFF)                 \
  ld16<(KOFF) * 2 + 0>(BUF[0], AP);          \
  ld16<(KOFF) * 2 + 64>(BUF[1], AP);         \
  ld16<(KOFF) * 2 + 128>(BUF[2], AP);        \
  ld16<(KOFF) * 2 + 192>(BUF[3], AP);        \
  ld16<(KOFF) * 2 + 256>(BUF[4], AP);        \
  ld16<(KOFF) * 2 + 320>(BUF[5], AP);        \
  ld16<(KOFF) * 2 + 384>(BUF[6], AP);        \
  ld16<(KOFF) * 2 + 448>(BUF[7], AP);

// Bounded LLC poll (all lanes same address -> 1 request).
__device__ __forceinline__ void spin_ctr(const int* p, int tgt, int* ab) {
  int it = 0;
  for (;;) {
    int v;
    asm volatile("global_load_dword %0, %1, off sc0 sc1\n\ts_waitcnt vmcnt(0)"
                 : "=v"(v) : "v"(p) : "memory");
    if (v >= tgt) return;
    if ((++it & 1023) == 0) {
      int a;
      asm volatile("global_load_dword %0, %1, off sc0 sc1\n\ts_waitcnt vmcnt(0)"
                   : "=v"(a) : "v"(ab) : "memory");
      if (a) return;
      if (it > (1 << 21)) {
        int one = 1;
        asm volatile("global_store_dword %0, %1, off sc0 sc1\n\ts_waitcnt vmcnt(0)"
                     :: "v"(ab), "v"(one) : "memory");
        return;
      }
    }
  }
}

__global__ void rnn_init(int* c) {
  // zero slot/ctr0/ctr1 (8 XCDs x 3 x 32 ints) + abort flag, at LLC scope
  for (int k = threadIdx.x; k < 772; k += 256) {
    int z = 0;
    asm volatile("global_store_dword %0, %1, off sc0 sc1"
                 :: "v"(c + k), "v"(z) : "memory");
  }
  asm volatile("s_waitcnt vmcnt(0)" ::: "memory");
}

__global__ __launch_bounds__(512) void rnn_main(
    const float* __restrict__ Xt, const float* __restrict__ W0,
    const float* __restrict__ b0, const float* __restrict__ W1,
    const float* __restrict__ b1, float* __restrict__ Y,
    ushort_t* hbuf, int* cnt) {
  __shared__ float part[2][4][16][17];  // [buf][ntile][row16][feat16+pad]
  __shared__ int s_slot;

  const int tid = threadIdx.x;
  const int wave = tid >> 6;
  const int lane = tid & 63;
  const int ln15 = lane & 15;
  const int lq = lane >> 4;
  const int n = wave & 3;
  const bool fin = wave < 4;  // finisher waves (h-half K, tanh, stores)

  uint32 xcc;
  asm("s_getreg_b32 %0, hwreg(HW_REG_XCC_ID)" : "=s"(xcc));
  const int xcd = xcc & 7;

  int* slotp  = cnt + xcd * 96;
  int* ctr0   = cnt + xcd * 96 + 32;
  int* ctr1   = cnt + xcd * 96 + 64;
  int* abortp = cnt + 768;

  if (tid == 0) {
    int one = 1, old;
    asm volatile("global_atomic_add %0, %1, %2, off sc0 sc1\n\ts_waitcnt vmcnt(0)"
                 : "=v"(old) : "v"(slotp), "v"(one) : "memory");
    s_slot = old & 31;
  }
  __syncthreads();
  const int slot = s_slot;
  const bool isL1 = slot >= 16;
  const int F0 = (slot & 15) * 64;
  const int fcol = F0 + n * 16 + ln15;
  const int row8 = ln15 & 7;  // batch row (MFMA rows 8-15 duplicate 0-7, discarded)

  // K-half owned by this wave:
  //  L0: fin -> h0(t-1) half (k 1024..2047), partial -> x half (k 0..1023)
  //  L1: fin -> h0(t) half (k 0..1023),     partial -> h1(t-1) half (k 1024..2047)
  const int kh = isL1 ? (fin ? 0 : 1) : (fin ? 1 : 0);
  const float* Wsrc = isL1 ? W1 : W0;

  // Load + pack this wave's weight slice into 32 B-frags (128 VGPRs).
  u32x4 bw[32];
  {
    const float* wp = Wsrc + (size_t)fcol * 2048 + kh * 1024 + lq * 8;
#pragma unroll 4
    for (int j = 0; j < 32; ++j) {
      f32x4 w0 = *(const f32x4*)(wp + j * 32);
      f32x4 w1 = *(const f32x4*)(wp + j * 32 + 4);
      bw[j] = pack8(w0, w1);
    }
  }
  const float bia = fin ? (isL1 ? b1 : b0)[fcol] : 0.f;

  ushort_t* h0b = hbuf + (size_t)xcd * 32768;  // [2][8][1024] bf16
  ushort_t* h1b = h0b + 16384;                 // [2][8][1024] bf16

  // K=1024 GEMM against L2-coherent h-state, double-buffered sc0 loads.
  auto gemm_h = [&](const ushort_t* hsrc) -> f32x4 {
    f32x4 a = {0.f, 0.f, 0.f, 0.f};
    const ushort_t* ap = hsrc + row8 * 1024 + lq * 8;
    u32x4 fa[8], fb[8];
    LOADB(fa, ap, 0);
    LOADB(fb, ap, 256);
    asm volatile("s_waitcnt vmcnt(8)" ::: "memory");
    __builtin_amdgcn_sched_barrier(0);
#pragma unroll
    for (int j = 0; j < 8; ++j) a = mfma_bf16(fa[j], bw[j], a);
    LOADB(fa, ap, 512);
    asm volatile("s_waitcnt vmcnt(8)" ::: "memory");
    __builtin_amdgcn_sched_barrier(0);
#pragma unroll
    for (int j = 0; j < 8; ++j) a = mfma_bf16(fb[j], bw[8 + j], a);
    LOADB(fb, ap, 768);
    asm volatile("s_waitcnt vmcnt(8)" ::: "memory");
    __builtin_amdgcn_sched_barrier(0);
#pragma unroll
    for (int j = 0; j < 8; ++j) a = mfma_bf16(fa[j], bw[16 + j], a);
    asm volatile("s_waitcnt vmcnt(0)" ::: "memory");
    __builtin_amdgcn_sched_barrier(0);
#pragma unroll
    for (int j = 0; j < 8; ++j) a = mfma_bf16(fb[j], bw[24 + j], a);
    return a;
  };

  // K=1024 GEMM against f32 X with on-the-fly bf16 pack (off critical path).
  auto gemm_x = [&](int t) -> f32x4 {
    f32x4 a = {0.f, 0.f, 0.f, 0.f};
    const float* xp = Xt + ((size_t)t * 64 + xcd * 8 + row8) * 1024 + lq * 8;
#pragma unroll 4
    for (int j = 0; j < 32; ++j) {
      f32x4 x0 = *(const f32x4*)(xp + j * 32);
      f32x4 x1 = *(const f32x4*)(xp + j * 32 + 4);
      a = mfma_bf16(pack8(x0, x1), bw[j], a);
    }
    return a;
  };

  for (int t = 0; t < 512; ++t) {
    const int buf = t & 1;
    const int pb = (t - 1) & 1;
    f32x4 acc = {0.f, 0.f, 0.f, 0.f};

    if (!isL1) {
      if (fin) {
        if (t >= 1) spin_ctr(ctr0, 16 * t, abortp);        // h0(t-1) ready
        if (t >= 2) spin_ctr(ctr1, 16 * (t - 1), abortp);  // h0 slot reusable
        if (t >= 1) acc = gemm_h(h0b + pb * 8192);
      } else {
        acc = gemm_x(t);
      }
    } else {
      if (fin) {
        if (t >= 1) spin_ctr(ctr1, 16 * t, abortp);        // own cohort done t-1
        spin_ctr(ctr0, 16 * (t + 1), abortp);              // h0(t) ready
        acc = gemm_h(h0b + buf * 8192);
      } else {
        if (t >= 1) {
          spin_ctr(ctr1, 16 * t, abortp);                  // h1(t-1) ready
          acc = gemm_h(h1b + pb * 8192);
        }
      }
    }

    if (!fin) {
#pragma unroll
      for (int r = 0; r < 4; ++r) part[buf][n][lq * 4 + r][ln15] = acc[r];
    }
    __syncthreads();  // partial tiles visible

    if (fin) {
      float o[4];
#pragma unroll
      for (int r = 0; r < 4; ++r) {
        float s = acc[r] + part[buf][n][lq * 4 + r][ln15] + bia;
        float ax = fabsf(s);
        float e = __expf(2.f * ax);                  // inf-safe
        float rr = 1.f - 2.f * __builtin_amdgcn_rcpf(e + 1.f);
        o[r] = copysignf(rr, s);
      }
      if (lq < 2) {  // valid batch rows 0..7
        ushort_t* hd = (isL1 ? h1b : h0b) + buf * 8192 + (lq * 4) * 1024 + fcol;
#pragma unroll
        for (int r = 0; r < 4; ++r) {
          uint32 hv = bf16rne(o[r]);
          asm volatile("global_store_short %0, %1, off sc0"
                       :: "v"(hd + r * 1024), "v"(hv) : "memory");
        }
        if (isL1) {
          float* yd = Y + ((size_t)t * 64 + xcd * 8 + lq * 4) * 1024 + fcol;
#pragma unroll
          for (int r = 0; r < 4; ++r) yd[r * 1024] = o[r];
        }
      }
      asm volatile("s_waitcnt vmcnt(0)" ::: "memory");  // h in L2, Y accepted
    }
    __syncthreads();  // all fin stores drained

    if (tid == 0) {
      int one = 1;
      int* cp = isL1 ? ctr1 : ctr0;
      asm volatile("global_atomic_add %0, %1, off sc1" :: "v"(cp), "v"(one) : "memory");
    }
  }
}

extern "C" void kernel_launch(void* const* d_in, const int* in_sizes, int n_in,
                              void* d_out, int out_size, void* d_ws, size_t ws_size,
                              hipStream_t stream) {
  const float* Xt = (const float*)d_in[0];
  const float* W0 = (const float*)d_in[1];
  const float* b0 = (const float*)d_in[2];
  const float* W1 = (const float*)d_in[3];
  const float* b1 = (const float*)d_in[4];
  float* Y = (float*)d_out;

  int* cnt = (int*)d_ws;                                   // 3088 B used
  ushort_t* hbuf = (ushort_t*)((char*)d_ws + 4096);        // 512 KB h-state

  rnn_init<<<1, 256, 0, stream>>>(cnt);
  rnn_main<<<256, 512, 0, stream>>>(Xt, W0, b0, W1, b1, Y, hbuf, cnt);
}